// Round 1
// baseline (2926.646 us; speedup 1.0000x reference)
//
#include <hip/hip_runtime.h>

// ---------------------------------------------------------------------------
// Flux double-stream block on MI355X (gfx950).
// Sizes: H=24, D=128, HS=3072, MLP=12288, LIMG=2048, LTXT=512, L=2560.
// Strategy: bf16 MFMA (16x16x32) for all GEMMs + flash attention; fp32
// elsewhere. Weights converted f32->bf16 (transposed to N x K) on the fly.
// ---------------------------------------------------------------------------

typedef unsigned short u16;
typedef unsigned int   u32;
typedef __attribute__((ext_vector_type(8))) short  short8;   // 8 x bf16 (4 VGPR)
typedef __attribute__((ext_vector_type(4))) float  floatx4;  // MFMA acc

#define MFMA16(a,b,c) __builtin_amdgcn_mfma_f32_16x16x32_bf16((a),(b),(c),0,0,0)

__device__ __forceinline__ u16 f2bf(float f) {
    u32 u = __float_as_uint(f);
    u32 r = (u + 0x7fffu + ((u >> 16) & 1u)) >> 16;   // RNE
    return (u16)r;
}

// async global->LDS, 16B per lane (wave-uniform LDS base + lane*16)
__device__ __forceinline__ void lds_load16(const void* g, void* l) {
    __builtin_amdgcn_global_load_lds(
        (const __attribute__((address_space(1))) u32*)g,
        (__attribute__((address_space(3))) u32*)l, 16, 0, 0);
}

// ---------------------------------------------------------------------------
// bias init for mod vectors (out = bias), N = 18432
__global__ void bias_init(const float* __restrict__ b, float* __restrict__ o) {
    int i = blockIdx.x * 256 + threadIdx.x;
    o[i] = b[i];
}

// mod GEMV: out[n] += sum_k silu(vec[k]) * W[k][n], K split over blockIdx.y (8 x 384)
__global__ void mod_gemv(const float* __restrict__ vec, const float* __restrict__ W,
                         float* __restrict__ out) {
    const int n  = blockIdx.x * 256 + threadIdx.x;
    const int k0 = blockIdx.y * 384;
    __shared__ float sl[384];
    for (int i = threadIdx.x; i < 384; i += 256) {
        float xv = vec[k0 + i];
        sl[i] = xv / (1.f + __expf(-xv));
    }
    __syncthreads();
    float acc = 0.f;
    const float* Wp = W + (size_t)k0 * 18432 + n;
    #pragma unroll 8
    for (int k = 0; k < 384; k++) acc += sl[k] * Wp[(size_t)k * 18432];
    atomicAdd(&out[n], acc);
}

// ---------------------------------------------------------------------------
// LayerNorm + modulation: out_bf16 = shift + (1+scale) * ln(x), rows of 3072
__global__ void ln_mod(const float* __restrict__ x, const float* __restrict__ shift,
                       const float* __restrict__ scale, u16* __restrict__ out) {
    const int row = blockIdx.x;
    const float* xr = x + (size_t)row * 3072;
    float v[12];
    float s = 0.f, s2 = 0.f;
    #pragma unroll
    for (int i = 0; i < 12; i++) {
        v[i] = xr[threadIdx.x + i * 256];
        s += v[i]; s2 += v[i] * v[i];
    }
    #pragma unroll
    for (int m = 1; m < 64; m <<= 1) { s += __shfl_xor(s, m); s2 += __shfl_xor(s2, m); }
    __shared__ float red[8];
    const int w = threadIdx.x >> 6;
    if ((threadIdx.x & 63) == 0) { red[w] = s; red[4 + w] = s2; }
    __syncthreads();
    s  = red[0] + red[1] + red[2] + red[3];
    s2 = red[4] + red[5] + red[6] + red[7];
    const float mean = s * (1.f / 3072.f);
    const float var  = s2 * (1.f / 3072.f) - mean * mean;
    const float rstd = rsqrtf(var + 1e-6f);
    u16* orow = out + (size_t)row * 3072;
    #pragma unroll
    for (int i = 0; i < 12; i++) {
        const int c = threadIdx.x + i * 256;
        orow[c] = f2bf(shift[c] + (1.f + scale[c]) * ((v[i] - mean) * rstd));
    }
}

// ---------------------------------------------------------------------------
// weight convert+transpose: W (K x N) f32  ->  Wt (N x K) bf16.  block (32,8)
__global__ void convT(const float* __restrict__ W, u16* __restrict__ Wt, int K, int N) {
    __shared__ u16 t[32][33];
    const int c0 = blockIdx.x * 32, r0 = blockIdx.y * 32;
    #pragma unroll
    for (int i = 0; i < 4; i++) {
        const int r = threadIdx.y + i * 8;
        t[r][threadIdx.x] = f2bf(W[(size_t)(r0 + r) * N + c0 + threadIdx.x]);
    }
    __syncthreads();
    #pragma unroll
    for (int i = 0; i < 4; i++) {
        const int c = threadIdx.y + i * 8;
        Wt[(size_t)(c0 + c) * K + r0 + threadIdx.x] = t[threadIdx.x][c];
    }
}

// ---------------------------------------------------------------------------
// GEMM: C(MxN) = A(MxK,bf16) * Wt(NxK,bf16)^T + bias, epilogues:
//   EPI 0: f32 out = v
//   EPI 1: bf16 out = gelu_tanh(v)
//   EPI 2: f32 out = res + gate[col]*v
// 128x128 tile, BK=32, 256 threads (4 waves x 64x64), global_load_lds staging.
template <int EPI>
__global__ __launch_bounds__(256) void gemm_bf16(
    const u16* __restrict__ A, const u16* __restrict__ Wt,
    const float* __restrict__ bias, const float* __restrict__ res,
    const float* __restrict__ gate, void* __restrict__ outp,
    int M, int N, int K)
{
    __shared__ __align__(16) u16 la[128 * 32];
    __shared__ __align__(16) u16 lb[128 * 32];
    const int tid = threadIdx.x;
    const int w = tid >> 6, ln = tid & 15, quad = (tid & 63) >> 4;
    const int m0 = blockIdx.y * 128, n0 = blockIdx.x * 128;
    const int wm = (w >> 1) * 64, wn = (w & 1) * 64;
    floatx4 acc[4][4] = {};
    const u16* Abase = A  + (size_t)m0 * K;
    const u16* Bbase = Wt + (size_t)n0 * K;

    for (int k0 = 0; k0 < K; k0 += 32) {
        #pragma unroll
        for (int p = 0; p < 2; p++) {
            const int c = p * 256 + tid;                 // 16B chunk id; 4 chunks/row
            lds_load16(Abase + (size_t)(c >> 2) * K + k0 + (c & 3) * 8, &la[c * 8]);
            lds_load16(Bbase + (size_t)(c >> 2) * K + k0 + (c & 3) * 8, &lb[c * 8]);
        }
        __syncthreads();
        short8 af[4], bf[4];
        #pragma unroll
        for (int i = 0; i < 4; i++) {
            af[i] = *(const short8*)&la[(wm + i * 16 + ln) * 32 + quad * 8];
            bf[i] = *(const short8*)&lb[(wn + i * 16 + ln) * 32 + quad * 8];
        }
        #pragma unroll
        for (int mi = 0; mi < 4; mi++)
            #pragma unroll
            for (int ni = 0; ni < 4; ni++)
                acc[mi][ni] = MFMA16(af[mi], bf[ni], acc[mi][ni]);
        __syncthreads();
    }

    #pragma unroll
    for (int ni = 0; ni < 4; ni++) {
        const int coln = n0 + wn + ni * 16 + ln;
        const float bv = bias[coln];
        float gv = 0.f;
        if constexpr (EPI == 2) gv = gate[coln];
        #pragma unroll
        for (int mi = 0; mi < 4; mi++) {
            #pragma unroll
            for (int r = 0; r < 4; r++) {
                const int rowm = m0 + wm + mi * 16 + quad * 4 + r;
                const size_t idx = (size_t)rowm * N + coln;
                float v = acc[mi][ni][r] + bv;
                if constexpr (EPI == 0) {
                    ((float*)outp)[idx] = v;
                } else if constexpr (EPI == 1) {
                    float g = 0.7978845608028654f * (v + 0.044715f * v * v * v);
                    float e = __expf(2.f * g);
                    float t = 1.f - 2.f / (e + 1.f);           // tanh(g), inf-safe
                    ((u16*)outp)[idx] = f2bf(0.5f * v * (1.f + t));
                } else {
                    ((float*)outp)[idx] = res[idx] + gv * v;
                }
            }
        }
    }
}

// ---------------------------------------------------------------------------
// fused RMS-norm + RoPE + bf16 pack. qkv f32 rows (L x [3,H,D]); one wave per
// (head, row); lane = rope pair p (d = 2p, 2p+1). Writes q/k/v as (H, L, D).
__global__ void qkv_post(const float* __restrict__ qkv, const float* __restrict__ qs,
                         const float* __restrict__ ks, const float* __restrict__ pe,
                         u16* __restrict__ qb, u16* __restrict__ kb, u16* __restrict__ vb,
                         int row0)
{
    const int h = blockIdx.x, l = row0 + (int)blockIdx.y;
    const int p = threadIdx.x;                       // 0..63
    const float* base = qkv + (size_t)l * 9216 + h * 128;
    float q0 = base[2 * p], q1 = base[2 * p + 1];
    float k0 = base[3072 + 2 * p], k1 = base[3072 + 2 * p + 1];
    float v0 = base[6144 + 2 * p], v1 = base[6144 + 2 * p + 1];
    float sq = q0 * q0 + q1 * q1, sk = k0 * k0 + k1 * k1;
    #pragma unroll
    for (int m = 1; m < 64; m <<= 1) { sq += __shfl_xor(sq, m); sk += __shfl_xor(sk, m); }
    const float rq = rsqrtf(sq * (1.f / 128.f) + 1e-6f);
    const float rk = rsqrtf(sk * (1.f / 128.f) + 1e-6f);
    q0 *= rq * qs[2 * p]; q1 *= rq * qs[2 * p + 1];
    k0 *= rk * ks[2 * p]; k1 *= rk * ks[2 * p + 1];
    const float4 pv = *(const float4*)(pe + (size_t)l * 256 + p * 4); // [c,-s,s,c]
    const float qo0 = pv.x * q0 + pv.y * q1, qo1 = pv.z * q0 + pv.w * q1;
    const float ko0 = pv.x * k0 + pv.y * k1, ko1 = pv.z * k0 + pv.w * k1;
    const size_t o = ((size_t)h * 2560 + l) * 128 + 2 * p;
    qb[o] = f2bf(qo0); qb[o + 1] = f2bf(qo1);
    kb[o] = f2bf(ko0); kb[o + 1] = f2bf(ko1);
    vb[o] = f2bf(v0);  vb[o + 1] = f2bf(v1);
}

// ---------------------------------------------------------------------------
// flash attention: grid (L/64, H), 256 thr. Each wave: 16 q-rows, online
// softmax over 32-key tiles. P round-trips LDS (C-layout -> A-layout).
// LDS strides padded (136 / 40) so b128 frag reads alias <= 2-way.
__global__ __launch_bounds__(256) void flash_attn(
    const u16* __restrict__ qb, const u16* __restrict__ kb, const u16* __restrict__ vb,
    u16* __restrict__ attn)
{
    const int qt = blockIdx.x, h = blockIdx.y;
    const int tid = threadIdx.x, w = tid >> 6, ln = tid & 15, quad = (tid & 63) >> 4;
    __shared__ __align__(16) u16 lk[32 * 136];       // K tile: [key][d], stride 136
    __shared__ __align__(16) u16 lv[128 * 40];       // V^T  : [d][key], stride 40
    __shared__ __align__(16) u16 lp[4][16 * 40];     // per-wave P, stride 40
    const size_t hbase = (size_t)h * 2560 * 128;
    const int qrow = qt * 64 + w * 16 + ln;
    short8 qf[4];
    #pragma unroll
    for (int d = 0; d < 4; d++)
        qf[d] = *(const short8*)(qb + hbase + (size_t)qrow * 128 + d * 32 + quad * 8);
    floatx4 of[8] = {};
    float mrun[4], lrun[4];
    #pragma unroll
    for (int r = 0; r < 4; r++) { mrun[r] = -1e30f; lrun[r] = 0.f; }
    const float scale = 0.08838834764831845f;        // 1/sqrt(128)
    const int key = tid >> 3, d0 = (tid & 7) * 16;   // staging role per thread

    for (int kt = 0; kt < 2560; kt += 32) {
        { // stage K (row-major, padded) and V^T
            const u16* kg = kb + hbase + (size_t)(kt + key) * 128 + d0;
            uint4 a0 = *(const uint4*)kg;
            uint4 a1 = *(const uint4*)(kg + 8);
            *(uint4*)&lk[key * 136 + d0]     = a0;
            *(uint4*)&lk[key * 136 + d0 + 8] = a1;
            const u16* vg = vb + hbase + (size_t)(kt + key) * 128 + d0;
            union { uint4 v4; u16 s[8]; } b0, b1;
            b0.v4 = *(const uint4*)vg;
            b1.v4 = *(const uint4*)(vg + 8);
            #pragma unroll
            for (int j = 0; j < 8; j++) {
                lv[(d0 + j) * 40 + key]     = b0.s[j];
                lv[(d0 + 8 + j) * 40 + key] = b1.s[j];
            }
        }
        __syncthreads();
        // S = Q K^T for 32 keys (two 16-col C-frags)
        floatx4 s0 = {0.f, 0.f, 0.f, 0.f}, s1 = {0.f, 0.f, 0.f, 0.f};
        #pragma unroll
        for (int d = 0; d < 4; d++) {
            short8 k0f = *(const short8*)&lk[ln * 136 + d * 32 + quad * 8];
            short8 k1f = *(const short8*)&lk[(16 + ln) * 136 + d * 32 + quad * 8];
            s0 = MFMA16(qf[d], k0f, s0);
            s1 = MFMA16(qf[d], k1f, s1);
        }
        // online softmax (rows quad*4+r; reduce across the 16 lanes of the quad)
        float p0[4], p1[4], alpha[4];
        #pragma unroll
        for (int r = 0; r < 4; r++) {
            float a0 = s0[r] * scale, a1 = s1[r] * scale;
            float mx = fmaxf(a0, a1);
            #pragma unroll
            for (int mm = 1; mm < 16; mm <<= 1) mx = fmaxf(mx, __shfl_xor(mx, mm, 16));
            const float mn = fmaxf(mrun[r], mx);
            a0 = __expf(a0 - mn); a1 = __expf(a1 - mn);
            float ps = a0 + a1;
            #pragma unroll
            for (int mm = 1; mm < 16; mm <<= 1) ps += __shfl_xor(ps, mm, 16);
            alpha[r] = __expf(mrun[r] - mn);
            lrun[r] = alpha[r] * lrun[r] + ps;
            mrun[r] = mn;
            p0[r] = a0; p1[r] = a1;
        }
        #pragma unroll
        for (int f = 0; f < 8; f++) {
            floatx4 o = of[f];
            o[0] *= alpha[0]; o[1] *= alpha[1]; o[2] *= alpha[2]; o[3] *= alpha[3];
            of[f] = o;
        }
        u16* lpw = &lp[w][0];
        #pragma unroll
        for (int r = 0; r < 4; r++) {
            lpw[(quad * 4 + r) * 40 + ln]      = f2bf(p0[r]);
            lpw[(quad * 4 + r) * 40 + 16 + ln] = f2bf(p1[r]);
        }
        __syncthreads();
        const short8 pf = *(const short8*)&lpw[ln * 40 + quad * 8];
        #pragma unroll
        for (int f = 0; f < 8; f++) {
            short8 vf = *(const short8*)&lv[(f * 16 + ln) * 40 + quad * 8];
            of[f] = MFMA16(pf, vf, of[f]);
        }
        __syncthreads();
    }
    const int orow = qt * 64 + w * 16 + quad * 4;
    #pragma unroll
    for (int f = 0; f < 8; f++)
        #pragma unroll
        for (int r = 0; r < 4; r++)
            attn[(size_t)(orow + r) * 3072 + h * 128 + f * 16 + ln] =
                f2bf(of[f][r] / lrun[r]);
}

// ---------------------------------------------------------------------------
extern "C" void kernel_launch(void* const* d_in, const int* in_sizes, int n_in,
                              void* d_out, int out_size, void* d_ws, size_t ws_size,
                              hipStream_t stream)
{
    (void)in_sizes; (void)n_in; (void)out_size; (void)ws_size;
    const float* img      = (const float*)d_in[0];
    const float* txt      = (const float*)d_in[1];
    const float* vec      = (const float*)d_in[2];
    const float* pe       = (const float*)d_in[3];
    const float* i_mod_w  = (const float*)d_in[4];
    const float* i_mod_b  = (const float*)d_in[5];
    const float* i_qkv_w  = (const float*)d_in[6];
    const float* i_qkv_b  = (const float*)d_in[7];
    const float* i_qs     = (const float*)d_in[8];
    const float* i_ks     = (const float*)d_in[9];
    const float* i_proj_w = (const float*)d_in[10];
    const float* i_proj_b = (const float*)d_in[11];
    const float* i_w1     = (const float*)d_in[12];
    const float* i_b1     = (const float*)d_in[13];
    const float* i_w2     = (const float*)d_in[14];
    const float* i_b2     = (const float*)d_in[15];
    const float* t_mod_w  = (const float*)d_in[16];
    const float* t_mod_b  = (const float*)d_in[17];
    const float* t_qkv_w  = (const float*)d_in[18];
    const float* t_qkv_b  = (const float*)d_in[19];
    const float* t_qs     = (const float*)d_in[20];
    const float* t_ks     = (const float*)d_in[21];
    const float* t_proj_w = (const float*)d_in[22];
    const float* t_proj_b = (const float*)d_in[23];
    const float* t_w1     = (const float*)d_in[24];
    const float* t_b1     = (const float*)d_in[25];
    const float* t_w2     = (const float*)d_in[26];
    const float* t_b2     = (const float*)d_in[27];

    float* out_img = (float*)d_out;                       // 2048 x 3072
    float* out_txt = out_img + (size_t)2048 * 3072;       // 512 x 3072

    // workspace layout (~237 MB)
    char* p = (char*)d_ws;
    u16*  WT   = (u16*)p;   p += (size_t)12288 * 3072 * 2;      // 75.5 MB (max weight, reused)
    float* MODI = (float*)p;                                     // 6*3072 img mod
    float* MODT = MODI + 18432;                                  // 6*3072 txt mod
    p += (size_t)2 * 18432 * 4;
    u16*  LNO  = (u16*)p;   p += (size_t)2560 * 3072 * 2;       // ln+mod out (reused for ln2)
    float* QKVF = (float*)p;                                     // qkv f32 (also reused as MID)
    u16*  MID  = (u16*)QKVF;                                     // mlp mid bf16 (2048x12288)
    p += (size_t)2560 * 9216 * 4;
    u16*  QB   = (u16*)p;
    u16*  KB   = QB + (size_t)24 * 2560 * 128;
    u16*  VB   = KB + (size_t)24 * 2560 * 128;
    p += (size_t)3 * 24 * 2560 * 128 * 2;
    u16*  ATTN = (u16*)p;                                        // 2560 x 3072 bf16

    const dim3 blk256(256), blkT(32, 8);

    // 1) modulation vectors
    bias_init<<<72, blk256, 0, stream>>>(i_mod_b, MODI);
    bias_init<<<72, blk256, 0, stream>>>(t_mod_b, MODT);
    mod_gemv<<<dim3(72, 8), blk256, 0, stream>>>(vec, i_mod_w, MODI);
    mod_gemv<<<dim3(72, 8), blk256, 0, stream>>>(vec, t_mod_w, MODT);

    // 2) LN1 + mod  (combined layout: txt rows 0..511, img rows 512..2559)
    ln_mod<<<512,  blk256, 0, stream>>>(txt, MODT,       MODT + 3072, LNO);
    ln_mod<<<2048, blk256, 0, stream>>>(img, MODI,       MODI + 3072, LNO + (size_t)512 * 3072);

    // 3) QKV GEMMs
    convT<<<dim3(288, 96), blkT, 0, stream>>>(i_qkv_w, WT, 3072, 9216);
    gemm_bf16<0><<<dim3(72, 16), blk256, 0, stream>>>(LNO + (size_t)512 * 3072, WT, i_qkv_b,
        nullptr, nullptr, QKVF + (size_t)512 * 9216, 2048, 9216, 3072);
    convT<<<dim3(288, 96), blkT, 0, stream>>>(t_qkv_w, WT, 3072, 9216);
    gemm_bf16<0><<<dim3(72, 4), blk256, 0, stream>>>(LNO, WT, t_qkv_b,
        nullptr, nullptr, QKVF, 512, 9216, 3072);

    // 4) RMS + RoPE + pack
    qkv_post<<<dim3(24, 512),  64, 0, stream>>>(QKVF, t_qs, t_ks, pe, QB, KB, VB, 0);
    qkv_post<<<dim3(24, 2048), 64, 0, stream>>>(QKVF, i_qs, i_ks, pe, QB, KB, VB, 512);

    // 5) attention
    flash_attn<<<dim3(40, 24), blk256, 0, stream>>>(QB, KB, VB, ATTN);

    // 6) proj + gated residual -> d_out
    convT<<<dim3(96, 96), blkT, 0, stream>>>(i_proj_w, WT, 3072, 3072);
    gemm_bf16<2><<<dim3(24, 16), blk256, 0, stream>>>(ATTN + (size_t)512 * 3072, WT, i_proj_b,
        img, MODI + 2 * 3072, out_img, 2048, 3072, 3072);
    convT<<<dim3(96, 96), blkT, 0, stream>>>(t_proj_w, WT, 3072, 3072);
    gemm_bf16<2><<<dim3(24, 4), blk256, 0, stream>>>(ATTN, WT, t_proj_b,
        txt, MODT + 2 * 3072, out_txt, 512, 3072, 3072);

    // 7) img MLP
    ln_mod<<<2048, blk256, 0, stream>>>(out_img, MODI + 3 * 3072, MODI + 4 * 3072, LNO);
    convT<<<dim3(384, 96), blkT, 0, stream>>>(i_w1, WT, 3072, 12288);
    gemm_bf16<1><<<dim3(96, 16), blk256, 0, stream>>>(LNO, WT, i_b1,
        nullptr, nullptr, MID, 2048, 12288, 3072);
    convT<<<dim3(96, 384), blkT, 0, stream>>>(i_w2, WT, 12288, 3072);
    gemm_bf16<2><<<dim3(24, 16), blk256, 0, stream>>>(MID, WT, i_b2,
        out_img, MODI + 5 * 3072, out_img, 2048, 3072, 12288);

    // 8) txt MLP
    ln_mod<<<512, blk256, 0, stream>>>(out_txt, MODT + 3 * 3072, MODT + 4 * 3072, LNO);
    convT<<<dim3(384, 96), blkT, 0, stream>>>(t_w1, WT, 3072, 12288);
    gemm_bf16<1><<<dim3(96, 4), blk256, 0, stream>>>(LNO, WT, t_b1,
        nullptr, nullptr, MID, 512, 12288, 3072);
    convT<<<dim3(96, 384), blkT, 0, stream>>>(t_w2, WT, 12288, 3072);
    gemm_bf16<2><<<dim3(24, 4), blk256, 0, stream>>>(MID, WT, t_b2,
        out_txt, MODT + 5 * 3072, out_txt, 512, 3072, 12288);
}